// Round 1
// baseline (3186.416 us; speedup 1.0000x reference)
//
#include <hip/hip_runtime.h>
#include <cstdint>

// Problem constants
// B=4, S=2048, E=1024, H=4, DH=256, DQ=256

// ======================= GEMM: C[M,N] = A[M,K] @ W[N,K]^T + bias =======================
// EPI: 0 = bias only, 1 = bias + exact GELU, 2 = blend: (0.9*aux + 0.1*(acc+bias))*2
template<int EPI>
__global__ __launch_bounds__(256)
void gemm_nt(const float* __restrict__ A, const float* __restrict__ W,
             const float* __restrict__ bias, float* __restrict__ C,
             int M, int N, int K, const float* __restrict__ aux) {
  constexpr int BM = 128, BN = 64, BK = 16, APAD = 132, BPAD = 68;
  __shared__ float As[BK * APAD];   // As[k][m]
  __shared__ float Bs[BK * BPAD];   // Bs[k][n]
  const int tid = threadIdx.x;
  const int tx = tid & 15, ty = tid >> 4;
  const int m0 = blockIdx.y * BM, n0 = blockIdx.x * BN;
  const int quad = tid & 3, arow = tid >> 2;   // arow 0..63

  const float* Ap0 = A + (size_t)(m0 + arow) * K + quad * 4;
  const float* Ap1 = Ap0 + (size_t)64 * K;
  const float* Wp  = W + (size_t)(n0 + arow) * K + quad * 4;

  float acc[8][4];
#pragma unroll
  for (int i = 0; i < 8; i++)
#pragma unroll
    for (int j = 0; j < 4; j++) acc[i][j] = 0.f;

  for (int k0 = 0; k0 < K; k0 += BK) {
    float4 a0 = *(const float4*)(Ap0 + k0);
    float4 a1 = *(const float4*)(Ap1 + k0);
    float4 bw = *(const float4*)(Wp + k0);
    __syncthreads();   // previous tile's compute done
#pragma unroll
    for (int i = 0; i < 4; i++) {
      As[(quad * 4 + i) * APAD + arow]      = ((const float*)&a0)[i];
      As[(quad * 4 + i) * APAD + arow + 64] = ((const float*)&a1)[i];
      Bs[(quad * 4 + i) * BPAD + arow]      = ((const float*)&bw)[i];
    }
    __syncthreads();
#pragma unroll
    for (int k = 0; k < BK; k++) {
      float4 av0 = *(float4*)&As[k * APAD + ty * 8];
      float4 av1 = *(float4*)&As[k * APAD + ty * 8 + 4];
      float4 bv  = *(float4*)&Bs[k * BPAD + tx * 4];
      const float* ap0 = (const float*)&av0;
      const float* ap1 = (const float*)&av1;
      const float* bp  = (const float*)&bv;
#pragma unroll
      for (int j = 0; j < 4; j++) {
        float b = bp[j];
#pragma unroll
        for (int i = 0; i < 4; i++) {
          acc[i][j]     += ap0[i] * b;
          acc[i + 4][j] += ap1[i] * b;
        }
      }
    }
  }

  const int crow = m0 + ty * 8;
  const int ccol = n0 + tx * 4;
  float bb[4];
#pragma unroll
  for (int j = 0; j < 4; j++) bb[j] = bias[ccol + j];
#pragma unroll
  for (int i = 0; i < 8; i++) {
    size_t idx = (size_t)(crow + i) * N + ccol;
    float4 o;
    float* op = (float*)&o;
#pragma unroll
    for (int j = 0; j < 4; j++) {
      float v = acc[i][j] + bb[j];
      if (EPI == 1) v = 0.5f * v * (1.0f + erff(v * 0.70710678118654752f));
      if (EPI == 2) v = (0.9f * aux[idx + j] + 0.1f * v) * 2.0f;
      op[j] = v;
    }
    *(float4*)(C + idx) = o;
  }
}

// ======================= Flash attention (fp32), H=4, DH=256 =======================
// qkv layout: [B,S,3E], q ch = h*256+d, k ch = 1024+h*256+d, v ch = 2048+h*256+d
// out: [B,S,E] with channel h*256+d
__global__ __launch_bounds__(256)
void flash_attn(const float* __restrict__ qkv, float* __restrict__ outp) {
  constexpr int BQ = 64, BKV = 64;
  __shared__ float Qs[64 * 256];
  __shared__ float KVs[64 * 256];
  __shared__ float Ps[64 * 68];
  const int tid = threadIdx.x;
  const int tx = tid & 15, ty = tid >> 4;
  const int bh = blockIdx.y;
  const int b = bh >> 2, h = bh & 3;
  const int q0 = blockIdx.x * BQ;
  const size_t rs = 3072;
  const float* qb = qkv + (size_t)b * 2048 * rs + (size_t)h * 256;
  const float* kb = qb + 1024;
  const float* vb = qb + 2048;
  const int dq = tid & 63;   // float4-block index 0..63 within a 256-wide row
  const int r0 = tid >> 6;   // 0..3

  // Load Q tile, pre-scaled by 1/sqrt(DH)=1/16, XOR-swizzled blocks
  for (int r = r0; r < BQ; r += 4) {
    float4 v = *(const float4*)(qb + (size_t)(q0 + r) * rs + dq * 4);
    v.x *= 0.0625f; v.y *= 0.0625f; v.z *= 0.0625f; v.w *= 0.0625f;
    int blk = dq ^ ((r >> 2) & 15);
    *(float4*)&Qs[r * 256 + blk * 4] = v;
  }

  float mrow[4], lrow[4], acc[4][16];
#pragma unroll
  for (int i = 0; i < 4; i++) {
    mrow[i] = -1e30f; lrow[i] = 0.f;
#pragma unroll
    for (int c = 0; c < 16; c++) acc[i][c] = 0.f;
  }

  for (int kv0 = 0; kv0 < 2048; kv0 += BKV) {
    __syncthreads();  // previous PV done reading KVs (and Q visible on first iter)
    for (int r = r0; r < BKV; r += 4) {
      float4 v = *(const float4*)(kb + (size_t)(kv0 + r) * rs + dq * 4);
      int blk = dq ^ ((r >> 2) & 15);
      *(float4*)&KVs[r * 256 + blk * 4] = v;
    }
    __syncthreads();

    // S = Q K^T  (rows ty*4+i, cols tx*4+j)
    float s[4][4];
#pragma unroll
    for (int i = 0; i < 4; i++)
#pragma unroll
      for (int j = 0; j < 4; j++) s[i][j] = 0.f;

#pragma unroll 2
    for (int d4 = 0; d4 < 64; ++d4) {
      float4 qv[4], kv4[4];
#pragma unroll
      for (int i = 0; i < 4; i++)
        qv[i] = *(float4*)&Qs[(ty * 4 + i) * 256 + ((d4 ^ ty) << 2)];
#pragma unroll
      for (int j = 0; j < 4; j++)
        kv4[j] = *(float4*)&KVs[(tx * 4 + j) * 256 + ((d4 ^ tx) << 2)];
#pragma unroll
      for (int i = 0; i < 4; i++)
#pragma unroll
        for (int j = 0; j < 4; j++)
          s[i][j] += qv[i].x * kv4[j].x + qv[i].y * kv4[j].y +
                     qv[i].z * kv4[j].z + qv[i].w * kv4[j].w;
    }

    // online softmax (row groups of 16 lanes share a q row set)
    float corr[4];
#pragma unroll
    for (int i = 0; i < 4; i++) {
      float mx = fmaxf(fmaxf(s[i][0], s[i][1]), fmaxf(s[i][2], s[i][3]));
#pragma unroll
      for (int msk = 1; msk < 16; msk <<= 1) mx = fmaxf(mx, __shfl_xor(mx, msk));
      float mnew = fmaxf(mrow[i], mx);
      corr[i] = __expf(mrow[i] - mnew);
      float rsum = 0.f;
#pragma unroll
      for (int j = 0; j < 4; j++) {
        float p = __expf(s[i][j] - mnew);
        s[i][j] = p; rsum += p;
      }
#pragma unroll
      for (int msk = 1; msk < 16; msk <<= 1) rsum += __shfl_xor(rsum, msk);
      lrow[i] = lrow[i] * corr[i] + rsum;
      mrow[i] = mnew;
      *(float4*)&Ps[(ty * 4 + i) * 68 + tx * 4] = make_float4(s[i][0], s[i][1], s[i][2], s[i][3]);
    }
    __syncthreads();  // K reads done, P visible

    // load V into KVs
    for (int r = r0; r < BKV; r += 4) {
      float4 v = *(const float4*)(vb + (size_t)(kv0 + r) * rs + dq * 4);
      int blk = dq ^ ((r >> 2) & 15);
      *(float4*)&KVs[r * 256 + blk * 4] = v;
    }
    // rescale accumulator (register-only, overlaps V load latency)
#pragma unroll
    for (int i = 0; i < 4; i++)
#pragma unroll
      for (int c = 0; c < 16; c++) acc[i][c] *= corr[i];
    __syncthreads();

    // O += P V   (thread owns 4 q rows x 16 d columns: d = (seg*16+tx)*4+c)
    for (int kv = 0; kv < BKV; ++kv) {
      int g = (kv >> 2) & 15;
      float p[4];
#pragma unroll
      for (int i = 0; i < 4; i++) p[i] = Ps[(ty * 4 + i) * 68 + kv];
#pragma unroll
      for (int seg = 0; seg < 4; ++seg) {
        float4 v = *(float4*)&KVs[kv * 256 + (((seg * 16 + tx) ^ g) << 2)];
#pragma unroll
        for (int i = 0; i < 4; i++) {
          acc[i][seg * 4 + 0] += p[i] * v.x;
          acc[i][seg * 4 + 1] += p[i] * v.y;
          acc[i][seg * 4 + 2] += p[i] * v.z;
          acc[i][seg * 4 + 3] += p[i] * v.w;
        }
      }
    }
  }

  float* ob = outp + (size_t)(b * 2048 + q0) * 1024 + h * 256;
#pragma unroll
  for (int i = 0; i < 4; i++) {
    float inv = 1.0f / lrow[i];
    int row = ty * 4 + i;
#pragma unroll
    for (int seg = 0; seg < 4; ++seg) {
      float4 o = make_float4(acc[i][seg * 4 + 0] * inv, acc[i][seg * 4 + 1] * inv,
                             acc[i][seg * 4 + 2] * inv, acc[i][seg * 4 + 3] * inv);
      *(float4*)(ob + (size_t)row * 1024 + (seg * 16 + tx) * 4) = o;
    }
  }
}

// ======================= Spectral attention =======================
__device__ inline float2 cmul(float2 a, float2 b) {
  return make_float2(a.x * b.x - a.y * b.y, a.x * b.y + a.y * b.x);
}

// one workgroup per (b, quaternion qd): 4 channels c0..c0+3, FFT length 2048 over seq
__global__ __launch_bounds__(256)
void spectral_kernel(const float* __restrict__ chol, const float* __restrict__ xin,
                     float* __restrict__ outp) {
  __shared__ float2 data[4][2048];   // 64 KB
  __shared__ float2 tw[1024];        // 8 KB, tw[t] = exp(-2*pi*i*t/2048)
  const int tid = threadIdx.x;
  const int b = blockIdx.x >> 8;     // DQ = 256
  const int qd = blockIdx.x & 255;
  const size_t c0 = (size_t)qd * 4;
  const float* cb = chol + (size_t)b * 2048 * 1024;

  for (int j = tid; j < 1024; j += 256) {
    float ang = -6.2831853071795864769f * (float)j * (1.0f / 2048.0f);
    float sv, cv; sincosf(ang, &sv, &cv);
    tw[j] = make_float2(cv, sv);
  }
  for (int s = tid; s < 2048; s += 256) {
    float4 v = *(const float4*)(cb + (size_t)s * 1024 + c0);
    data[0][s] = make_float2(v.x, 0.f);
    data[1][s] = make_float2(v.y, 0.f);
    data[2][s] = make_float2(v.z, 0.f);
    data[3][s] = make_float2(v.w, 0.f);
  }
  __syncthreads();

  // forward radix-2 DIF: natural in -> bit-reversed out
  for (int lh = 10; lh >= 0; --lh) {
    const int half = 1 << lh;
#pragma unroll 1
    for (int it = 0; it < 16; ++it) {
      int g = it * 256 + tid;          // 0..4095 : 4 comps x 1024 butterflies
      int c = g >> 10;
      int bf = g & 1023;
      int j = bf & (half - 1);
      int base = ((bf >> lh) << (lh + 1)) | j;
      float2 a = data[c][base];
      float2 bb = data[c][base + half];
      float2 sum = make_float2(a.x + bb.x, a.y + bb.y);
      float2 dif = make_float2(a.x - bb.x, a.y - bb.y);
      float2 w = tw[j << (10 - lh)];
      data[c][base] = sum;
      data[c][base + half] = cmul(dif, w);
    }
    __syncthreads();
  }

  // per-frequency filter + quaternion cube (closed form)
#pragma unroll 1
  for (int it = 0; it < 8; ++it) {
    int p = it * 256 + tid;
    unsigned k = __brev((unsigned)p) >> 21;   // 11-bit reverse -> true frequency
    float ang = 1.5f * atanf(logf((float)k + 1e-10f));
    float fs, fc; sincosf(ang, &fs, &fc);
    float2 f = make_float2(fc, fs);
    float2 a  = cmul(data[0][p], f);
    float2 xq = cmul(data[1][p], f);
    float2 yq = cmul(data[2][p], f);
    float2 zq = cmul(data[3][p], f);
    float2 a2 = cmul(a, a);
    float2 sx = cmul(xq, xq), sy = cmul(yq, yq), sz = cmul(zq, zq);
    float2 s  = make_float2(sx.x + sy.x + sz.x, sx.y + sy.y + sz.y);
    float2 t3 = make_float2(a2.x - 3.f * s.x, a2.y - 3.f * s.y);   // a^2 - 3s
    float2 cf = make_float2(3.f * a2.x - s.x, 3.f * a2.y - s.y);   // 3a^2 - s
    data[0][p] = cmul(a, t3);
    data[1][p] = cmul(cf, xq);
    data[2][p] = cmul(cf, yq);
    data[3][p] = cmul(cf, zq);
  }
  __syncthreads();

  // inverse radix-2 DIT: bit-reversed in -> natural out (conj twiddles; scale 1/N at end)
  for (int lh = 0; lh <= 10; ++lh) {
    const int half = 1 << lh;
#pragma unroll 1
    for (int it = 0; it < 16; ++it) {
      int g = it * 256 + tid;
      int c = g >> 10;
      int bf = g & 1023;
      int j = bf & (half - 1);
      int base = ((bf >> lh) << (lh + 1)) | j;
      float2 a = data[c][base];
      float2 bb = data[c][base + half];
      float2 w = tw[j << (10 - lh)];
      w.y = -w.y;
      float2 bw = cmul(bb, w);
      data[c][base] = make_float2(a.x + bw.x, a.y + bw.y);
      data[c][base + half] = make_float2(a.x - bw.x, a.y - bw.y);
    }
    __syncthreads();
  }

  const float* xb = xin + (size_t)b * 2048 * 1024;
  float* ob = outp + (size_t)b * 2048 * 1024;
  const float inv = 1.0f / 2048.0f;
  for (int s = tid; s < 2048; s += 256) {
    float4 xv = *(const float4*)(xb + (size_t)s * 1024 + c0);
    float4 o;
    o.x = xv.x * data[0][s].x * inv;
    o.y = xv.y * data[1][s].x * inv;
    o.z = xv.z * data[2][s].x * inv;
    o.w = xv.w * data[3][s].x * inv;
    *(float4*)(ob + (size_t)s * 1024 + c0) = o;
  }
}

// ======================= launch =======================
extern "C" void kernel_launch(void* const* d_in, const int* in_sizes, int n_in,
                              void* d_out, int out_size, void* d_ws, size_t ws_size,
                              hipStream_t stream) {
  const float* x    = (const float*)d_in[0];
  const float* wqkv = (const float*)d_in[1];
  const float* bqkv = (const float*)d_in[2];
  const float* wout = (const float*)d_in[3];
  const float* bout = (const float*)d_in[4];
  const float* w1   = (const float*)d_in[5];
  const float* b1   = (const float*)d_in[6];
  const float* w2   = (const float*)d_in[7];
  const float* b2   = (const float*)d_in[8];
  float* out = (float*)d_out;
  float* ws  = (float*)d_ws;

  // workspace layout (floats): qkv 96MB | attn 32MB | h 32MB | nico 32MB ; chol reuses qkv
  float* qkv  = ws;
  float* attn = ws + 25165824;
  float* hbuf = ws + 33554432;
  float* nico = ws + 41943040;
  float* chol = ws;   // qkv dead after flash_attn

  // 1) qkv = x @ Wqkv^T + b
  gemm_nt<0><<<dim3(48, 64), 256, 0, stream>>>(x, wqkv, bqkv, qkv, 8192, 3072, 1024, nullptr);
  // 2) attention
  flash_attn<<<dim3(32, 16), 256, 0, stream>>>(qkv, attn);
  // 3) nicotinic = attn @ Wout^T + b
  gemm_nt<0><<<dim3(16, 64), 256, 0, stream>>>(attn, wout, bout, nico, 8192, 1024, 1024, nullptr);
  // 4) h = gelu(x @ W1^T + b1)
  gemm_nt<1><<<dim3(16, 64), 256, 0, stream>>>(x, w1, b1, hbuf, 8192, 1024, 1024, nullptr);
  // 5) chol2 = (0.9*nico + 0.1*(h @ W2^T + b2)) * 2
  gemm_nt<2><<<dim3(16, 64), 256, 0, stream>>>(hbuf, w2, b2, chol, 8192, 1024, 1024, nico);
  // 6) out = x * spectral(chol2)
  spectral_kernel<<<1024, 256, 0, stream>>>(chol, x, out);
}

// Round 2
// 2017.832 us; speedup vs baseline: 1.5791x; 1.5791x over previous
//
#include <hip/hip_runtime.h>
#include <cstdint>

// Problem constants: B=4, S=2048, E=1024, H=4, DH=256, DQ=256
typedef unsigned short u16;
typedef __attribute__((ext_vector_type(8))) short bf16x8;
typedef __attribute__((ext_vector_type(4))) float f32x4;

__device__ inline u16 f2bf(float f) {
  unsigned u = __float_as_uint(f);
  return (u16)((u + 0x7fffu + ((u >> 16) & 1u)) >> 16);
}
__device__ inline float bf2f(u16 h) { return __uint_as_float((unsigned)h << 16); }

#define MFMA16(a, b, c) __builtin_amdgcn_mfma_f32_16x16x32_bf16(a, b, c, 0, 0, 0)

// ======================= GEMM: C[M,N] = A[M,K] @ W[N,K]^T + bias (fp32, unchanged) =======================
template<int EPI>
__global__ __launch_bounds__(256)
void gemm_nt(const float* __restrict__ A, const float* __restrict__ W,
             const float* __restrict__ bias, float* __restrict__ C,
             int M, int N, int K, const float* __restrict__ aux) {
  constexpr int BK = 16, APAD = 132, BPAD = 68;
  __shared__ float As[BK * APAD];
  __shared__ float Bs[BK * BPAD];
  const int tid = threadIdx.x;
  const int tx = tid & 15, ty = tid >> 4;
  const int m0 = blockIdx.y * 128, n0 = blockIdx.x * 64;
  const int quad = tid & 3, arow = tid >> 2;

  const float* Ap0 = A + (size_t)(m0 + arow) * K + quad * 4;
  const float* Ap1 = Ap0 + (size_t)64 * K;
  const float* Wp  = W + (size_t)(n0 + arow) * K + quad * 4;

  float acc[8][4];
#pragma unroll
  for (int i = 0; i < 8; i++)
#pragma unroll
    for (int j = 0; j < 4; j++) acc[i][j] = 0.f;

  for (int k0 = 0; k0 < K; k0 += BK) {
    float4 a0 = *(const float4*)(Ap0 + k0);
    float4 a1 = *(const float4*)(Ap1 + k0);
    float4 bw = *(const float4*)(Wp + k0);
    __syncthreads();
#pragma unroll
    for (int i = 0; i < 4; i++) {
      As[(quad * 4 + i) * APAD + arow]      = ((const float*)&a0)[i];
      As[(quad * 4 + i) * APAD + arow + 64] = ((const float*)&a1)[i];
      Bs[(quad * 4 + i) * BPAD + arow]      = ((const float*)&bw)[i];
    }
    __syncthreads();
#pragma unroll
    for (int k = 0; k < BK; k++) {
      float4 av0 = *(float4*)&As[k * APAD + ty * 8];
      float4 av1 = *(float4*)&As[k * APAD + ty * 8 + 4];
      float4 bv  = *(float4*)&Bs[k * BPAD + tx * 4];
      const float* ap0 = (const float*)&av0;
      const float* ap1 = (const float*)&av1;
      const float* bp  = (const float*)&bv;
#pragma unroll
      for (int j = 0; j < 4; j++) {
        float b = bp[j];
#pragma unroll
        for (int i = 0; i < 4; i++) {
          acc[i][j]     += ap0[i] * b;
          acc[i + 4][j] += ap1[i] * b;
        }
      }
    }
  }

  const int crow = m0 + ty * 8;
  const int ccol = n0 + tx * 4;
  float bb[4];
#pragma unroll
  for (int j = 0; j < 4; j++) bb[j] = bias[ccol + j];
#pragma unroll
  for (int i = 0; i < 8; i++) {
    size_t idx = (size_t)(crow + i) * N + ccol;
    float4 o;
    float* op = (float*)&o;
#pragma unroll
    for (int j = 0; j < 4; j++) {
      float v = acc[i][j] + bb[j];
      if (EPI == 1) v = 0.5f * v * (1.0f + erff(v * 0.70710678118654752f));
      if (EPI == 2) v = (0.9f * aux[idx + j] + 0.1f * v) * 2.0f;
      op[j] = v;
    }
    *(float4*)(C + idx) = o;
  }
}

// ======================= split qkv -> bf16 hi/lo (Q scaled by 1/16*log2e), V transposed =======================
__global__ __launch_bounds__(256)
void split_qkv(const float* __restrict__ qkv,
               u16* __restrict__ Qh, u16* __restrict__ Ql,
               u16* __restrict__ Kh, u16* __restrict__ Kl,
               u16* __restrict__ Vth, u16* __restrict__ Vtl) {
  __shared__ unsigned vlds[64][65];
  const int tid = threadIdx.x;
  const int bx = blockIdx.x;
  const int bh = bx >> 5, st = bx & 31;
  const int b = bh >> 2, h = bh & 3;
  const int s0 = st * 64;
  const float QSCALE = 0.0625f * 1.44269504088896341f;

  // Q, K rows (coalesced)
#pragma unroll 1
  for (int i = 0; i < 64; ++i) {
    size_t srow = (size_t)(b * 2048 + s0 + i) * 3072;
    size_t orow = ((size_t)bh * 2048 + s0 + i) * 256 + tid;
    float q = qkv[srow + h * 256 + tid] * QSCALE;
    u16 qhi = f2bf(q);
    Qh[orow] = qhi;
    Ql[orow] = f2bf(q - bf2f(qhi));
    float k = qkv[srow + 1024 + h * 256 + tid];
    u16 khi = f2bf(k);
    Kh[orow] = khi;
    Kl[orow] = f2bf(k - bf2f(khi));
  }
  // V transpose through LDS, 4 chunks of 64 d
#pragma unroll 1
  for (int dc = 0; dc < 4; ++dc) {
    __syncthreads();
#pragma unroll 1
    for (int i = 0; i < 16; ++i) {
      int idx = i * 256 + tid;
      int s = idx >> 6, dl = idx & 63;
      float v = qkv[(size_t)(b * 2048 + s0 + s) * 3072 + 2048 + h * 256 + dc * 64 + dl];
      u16 vh_ = f2bf(v);
      u16 vl_ = f2bf(v - bf2f(vh_));
      vlds[dl][s] = (unsigned)vh_ | ((unsigned)vl_ << 16);
    }
    __syncthreads();
#pragma unroll 1
    for (int i = 0; i < 16; ++i) {
      int idx = i * 256 + tid;
      int dl = idx >> 6, s = idx & 63;
      unsigned u = vlds[dl][s];
      size_t orow = ((size_t)bh * 256 + dc * 64 + dl) * 2048 + s0 + s;
      Vth[orow] = (u16)u;
      Vtl[orow] = (u16)(u >> 16);
    }
  }
}

// ======================= MFMA flash attention =======================
// 8 waves x 16 q-rows (BQ=128), TKV=32, double-buffered K/V in LDS, 3-product bf16 split.
// LDS shorts: buf0 @0 {Kh[32][256]@0, Kl@8192, Vth[256][32]@16384, Vtl@24576}, buf1 @32768,
//             P @65536: wave w: ph[16][40] @65536+w*1280, pl @+640.
__global__ __launch_bounds__(512, 2)
void flash_mfma(const u16* __restrict__ Qh, const u16* __restrict__ Ql,
                const u16* __restrict__ Kh, const u16* __restrict__ Kl,
                const u16* __restrict__ Vth, const u16* __restrict__ Vtl,
                float* __restrict__ outp) {
  __shared__ __align__(16) u16 lds[75776];
  const int tid = threadIdx.x;
  const int lane = tid & 63, w = tid >> 6;
  const int g = lane >> 4, lm = lane & 15;
  const int raw = blockIdx.x;
  const int bh = (raw & 7) + 8 * (raw >> 7);     // all 16 q-tiles of a (b,h) on one XCD
  const int qt = (raw >> 3) & 15;
  const int q0 = qt * 128 + w * 16;
  const size_t bhS = (size_t)bh * 2048;

  // Q fragments in registers (loaded once)
  bf16x8 qh[8], ql[8];
  {
    const u16* qp  = Qh + (bhS + q0 + lm) * 256 + g * 8;
    const u16* qp2 = Ql + (bhS + q0 + lm) * 256 + g * 8;
#pragma unroll
    for (int c = 0; c < 8; ++c) {
      qh[c] = *(const bf16x8*)(qp + c * 32);
      ql[c] = *(const bf16x8*)(qp2 + c * 32);
    }
  }

  // staging descriptors: 8x 16B units per thread -> 64 KB tile
  const u16* src[8];
  int sstr[8];
  int dst[8];
#pragma unroll
  for (int i = 0; i < 8; ++i) {
    int unit = i * 512 + tid;
    int region = unit >> 10, uo = unit & 1023;
    if (region < 2) {
      int kv = uo >> 5, ds = uo & 31;
      src[i] = (region ? Kl : Kh) + (bhS + kv) * 256 + ds * 8;
      sstr[i] = 32 * 256;
    } else {
      int d = uo >> 2, sl = uo & 3;
      src[i] = (region == 2 ? Vth : Vtl) + ((size_t)bh * 256 + d) * 2048 + sl * 8;
      sstr[i] = 32;
    }
    dst[i] = unit * 8;
  }

  f32x4 o[16];
#pragma unroll
  for (int f = 0; f < 16; ++f) o[f] = (f32x4){0.f, 0.f, 0.f, 0.f};
  float m[4] = {-3e38f, -3e38f, -3e38f, -3e38f};
  float l[4] = {0.f, 0.f, 0.f, 0.f};

  // prologue: stage tile 0 into buf0
#pragma unroll
  for (int i = 0; i < 8; ++i) {
    int4 v = *(const int4*)src[i];
    *(int4*)&lds[dst[i]] = v;
  }
  __syncthreads();

  u16* php = &lds[65536 + w * 1280];
  u16* plp = php + 640;

#pragma unroll 1
  for (int t = 0; t < 64; ++t) {
    const int cur = (t & 1) * 32768;
    int4 nxt[8];
    if (t < 63) {
#pragma unroll
      for (int i = 0; i < 8; ++i) {
        src[i] += sstr[i];
        nxt[i] = *(const int4*)src[i];      // issue early; written to LDS after barrier
      }
    }
    const u16* kh_ = &lds[cur];
    const u16* kl_ = &lds[cur + 8192];
    const u16* vh_ = &lds[cur + 16384];
    const u16* vl_ = &lds[cur + 24576];

    // ---- scores: S[q][kv] (16x32), 3-product split, two independent acc chains ----
    f32x4 s0 = {0.f, 0.f, 0.f, 0.f}, s1 = {0.f, 0.f, 0.f, 0.f};
    {
      const u16* k0h = kh_ + lm * 256 + g * 8;
      const u16* k1h = kh_ + (16 + lm) * 256 + g * 8;
      const u16* k0l = kl_ + lm * 256 + g * 8;
      const u16* k1l = kl_ + (16 + lm) * 256 + g * 8;
#pragma unroll
      for (int c = 0; c < 8; ++c) {
        bf16x8 b0h = *(const bf16x8*)(k0h + c * 32);
        bf16x8 b1h = *(const bf16x8*)(k1h + c * 32);
        bf16x8 b0l = *(const bf16x8*)(k0l + c * 32);
        bf16x8 b1l = *(const bf16x8*)(k1l + c * 32);
        s0 = MFMA16(qh[c], b0h, s0);
        s1 = MFMA16(qh[c], b1h, s1);
        s0 = MFMA16(qh[c], b0l, s0);
        s1 = MFMA16(qh[c], b1l, s1);
        s0 = MFMA16(ql[c], b0h, s0);
        s1 = MFMA16(ql[c], b1h, s1);
      }
    }

    // ---- online softmax (scores already in log2 domain) ----
    float corr[4], p0[4], p1[4];
#pragma unroll
    for (int r = 0; r < 4; ++r) {
      float mx = fmaxf(s0[r], s1[r]);
      mx = fmaxf(mx, __shfl_xor(mx, 1));
      mx = fmaxf(mx, __shfl_xor(mx, 2));
      mx = fmaxf(mx, __shfl_xor(mx, 4));
      mx = fmaxf(mx, __shfl_xor(mx, 8));
      float mn = fmaxf(m[r], mx);
      corr[r] = exp2f(m[r] - mn);
      m[r] = mn;
      p0[r] = exp2f(s0[r] - mn);
      p1[r] = exp2f(s1[r] - mn);
      float rs = p0[r] + p1[r];
      rs += __shfl_xor(rs, 1);
      rs += __shfl_xor(rs, 2);
      rs += __shfl_xor(rs, 4);
      rs += __shfl_xor(rs, 8);
      l[r] = l[r] * corr[r] + rs;
    }

    // ---- P split + LDS transpose bounce (C-layout -> A-frag layout) ----
#pragma unroll
    for (int r = 0; r < 4; ++r) {
      int q = g * 4 + r;
      u16 h0 = f2bf(p0[r]);
      php[q * 40 + lm] = h0;
      plp[q * 40 + lm] = f2bf(p0[r] - bf2f(h0));
      u16 h1 = f2bf(p1[r]);
      php[q * 40 + 16 + lm] = h1;
      plp[q * 40 + 16 + lm] = f2bf(p1[r] - bf2f(h1));
    }
    // rescale O while P writes land
#pragma unroll
    for (int f = 0; f < 16; ++f) {
#pragma unroll
      for (int r = 0; r < 4; ++r) o[f][r] *= corr[r];
    }
    bf16x8 pah = *(const bf16x8*)(php + lm * 40 + g * 8);
    bf16x8 pal = *(const bf16x8*)(plp + lm * 40 + g * 8);

    // ---- PV: O[q][d] += P V, 16 d-frags, 3-product ----
#pragma unroll
    for (int f = 0; f < 16; ++f) {
      bf16x8 bvh = *(const bf16x8*)(vh_ + (f * 16 + lm) * 32 + g * 8);
      bf16x8 bvl = *(const bf16x8*)(vl_ + (f * 16 + lm) * 32 + g * 8);
      o[f] = MFMA16(pah, bvh, o[f]);
      o[f] = MFMA16(pah, bvl, o[f]);
      o[f] = MFMA16(pal, bvh, o[f]);
    }

    __syncthreads();
    if (t < 63) {
      const int nb = ((t + 1) & 1) * 32768;
#pragma unroll
      for (int i = 0; i < 8; ++i) *(int4*)&lds[nb + dst[i]] = nxt[i];
    }
    __syncthreads();
  }

  // epilogue
  const int b = bh >> 2, h = bh & 3;
  float* ob = outp + (size_t)(b * 2048 + q0) * 1024 + h * 256;
  float inv[4];
#pragma unroll
  for (int r = 0; r < 4; ++r) inv[r] = 1.0f / l[r];
#pragma unroll
  for (int f = 0; f < 16; ++f) {
#pragma unroll
    for (int r = 0; r < 4; ++r)
      ob[(size_t)(g * 4 + r) * 1024 + f * 16 + lm] = o[f][r] * inv[r];
  }
}

// ======================= Spectral attention (unchanged) =======================
__device__ inline float2 cmul(float2 a, float2 b) {
  return make_float2(a.x * b.x - a.y * b.y, a.x * b.y + a.y * b.x);
}

__global__ __launch_bounds__(256)
void spectral_kernel(const float* __restrict__ chol, const float* __restrict__ xin,
                     float* __restrict__ outp) {
  __shared__ float2 data[4][2048];
  __shared__ float2 tw[1024];
  const int tid = threadIdx.x;
  const int b = blockIdx.x >> 8;
  const int qd = blockIdx.x & 255;
  const size_t c0 = (size_t)qd * 4;
  const float* cb = chol + (size_t)b * 2048 * 1024;

  for (int j = tid; j < 1024; j += 256) {
    float ang = -6.2831853071795864769f * (float)j * (1.0f / 2048.0f);
    float sv, cv; sincosf(ang, &sv, &cv);
    tw[j] = make_float2(cv, sv);
  }
  for (int s = tid; s < 2048; s += 256) {
    float4 v = *(const float4*)(cb + (size_t)s * 1024 + c0);
    data[0][s] = make_float2(v.x, 0.f);
    data[1][s] = make_float2(v.y, 0.f);
    data[2][s] = make_float2(v.z, 0.f);
    data[3][s] = make_float2(v.w, 0.f);
  }
  __syncthreads();

  for (int lh = 10; lh >= 0; --lh) {
    const int half = 1 << lh;
#pragma unroll 1
    for (int it = 0; it < 16; ++it) {
      int gg = it * 256 + tid;
      int c = gg >> 10;
      int bf = gg & 1023;
      int j = bf & (half - 1);
      int base = ((bf >> lh) << (lh + 1)) | j;
      float2 a = data[c][base];
      float2 bb = data[c][base + half];
      float2 sum = make_float2(a.x + bb.x, a.y + bb.y);
      float2 dif = make_float2(a.x - bb.x, a.y - bb.y);
      float2 wv = tw[j << (10 - lh)];
      data[c][base] = sum;
      data[c][base + half] = cmul(dif, wv);
    }
    __syncthreads();
  }

#pragma unroll 1
  for (int it = 0; it < 8; ++it) {
    int p = it * 256 + tid;
    unsigned k = __brev((unsigned)p) >> 21;
    float ang = 1.5f * atanf(logf((float)k + 1e-10f));
    float fs, fc; sincosf(ang, &fs, &fc);
    float2 f = make_float2(fc, fs);
    float2 a  = cmul(data[0][p], f);
    float2 xq = cmul(data[1][p], f);
    float2 yq = cmul(data[2][p], f);
    float2 zq = cmul(data[3][p], f);
    float2 a2 = cmul(a, a);
    float2 sx = cmul(xq, xq), sy = cmul(yq, yq), sz = cmul(zq, zq);
    float2 s  = make_float2(sx.x + sy.x + sz.x, sx.y + sy.y + sz.y);
    float2 t3 = make_float2(a2.x - 3.f * s.x, a2.y - 3.f * s.y);
    float2 cf = make_float2(3.f * a2.x - s.x, 3.f * a2.y - s.y);
    data[0][p] = cmul(a, t3);
    data[1][p] = cmul(cf, xq);
    data[2][p] = cmul(cf, yq);
    data[3][p] = cmul(cf, zq);
  }
  __syncthreads();

  for (int lh = 0; lh <= 10; ++lh) {
    const int half = 1 << lh;
#pragma unroll 1
    for (int it = 0; it < 16; ++it) {
      int gg = it * 256 + tid;
      int c = gg >> 10;
      int bf = gg & 1023;
      int j = bf & (half - 1);
      int base = ((bf >> lh) << (lh + 1)) | j;
      float2 a = data[c][base];
      float2 bb = data[c][base + half];
      float2 wv = tw[j << (10 - lh)];
      wv.y = -wv.y;
      float2 bw = cmul(bb, wv);
      data[c][base] = make_float2(a.x + bw.x, a.y + bw.y);
      data[c][base + half] = make_float2(a.x - bw.x, a.y - bw.y);
    }
    __syncthreads();
  }

  const float* xb = xin + (size_t)b * 2048 * 1024;
  float* ob = outp + (size_t)b * 2048 * 1024;
  const float inv = 1.0f / 2048.0f;
  for (int s = tid; s < 2048; s += 256) {
    float4 xv = *(const float4*)(xb + (size_t)s * 1024 + c0);
    float4 o;
    o.x = xv.x * data[0][s].x * inv;
    o.y = xv.y * data[1][s].x * inv;
    o.z = xv.z * data[2][s].x * inv;
    o.w = xv.w * data[3][s].x * inv;
    *(float4*)(ob + (size_t)s * 1024 + c0) = o;
  }
}

// ======================= launch =======================
extern "C" void kernel_launch(void* const* d_in, const int* in_sizes, int n_in,
                              void* d_out, int out_size, void* d_ws, size_t ws_size,
                              hipStream_t stream) {
  const float* x    = (const float*)d_in[0];
  const float* wqkv = (const float*)d_in[1];
  const float* bqkv = (const float*)d_in[2];
  const float* wout = (const float*)d_in[3];
  const float* bout = (const float*)d_in[4];
  const float* w1   = (const float*)d_in[5];
  const float* b1   = (const float*)d_in[6];
  const float* w2   = (const float*)d_in[7];
  const float* b2   = (const float*)d_in[8];
  float* out = (float*)d_out;
  float* ws  = (float*)d_ws;

  // Workspace (192 MB):
  //   region A [0, 96MB): qkv fp32 -> later attn (32MB) | nico (32MB) | h (32MB)
  //   region D [96MB, 192MB): Qh,Ql,Kh,Kl,Vth,Vtl (6 x 16MB bf16) -> later chol (32MB)
  float* qkv  = ws;
  u16* Qh  = (u16*)((char*)d_ws + 100663296);
  u16* Ql  = Qh + 8388608;
  u16* Kh  = Ql + 8388608;
  u16* Kl  = Kh + 8388608;
  u16* Vth = Kl + 8388608;
  u16* Vtl = Vth + 8388608;
  float* attn = ws;                    // overlays qkv (dead after split)
  float* nico = ws + 8388608;
  float* hbuf = ws + 16777216;
  float* chol = (float*)((char*)d_ws + 100663296);  // overlays splits (dead after flash)

  // 1) qkv = x @ Wqkv^T + b
  gemm_nt<0><<<dim3(48, 64), 256, 0, stream>>>(x, wqkv, bqkv, qkv, 8192, 3072, 1024, nullptr);
  // 2) split to bf16 hi/lo (+ V transpose)
  split_qkv<<<dim3(512), 256, 0, stream>>>(qkv, Qh, Ql, Kh, Kl, Vth, Vtl);
  // 3) MFMA flash attention
  flash_mfma<<<dim3(256), 512, 0, stream>>>(Qh, Ql, Kh, Kl, Vth, Vtl, attn);
  // 4) nicotinic = attn @ Wout^T + b
  gemm_nt<0><<<dim3(16, 64), 256, 0, stream>>>(attn, wout, bout, nico, 8192, 1024, 1024, nullptr);
  // 5) h = gelu(x @ W1^T + b1)
  gemm_nt<1><<<dim3(16, 64), 256, 0, stream>>>(x, w1, b1, hbuf, 8192, 1024, 1024, nullptr);
  // 6) chol2 = (0.9*nico + 0.1*(h @ W2^T + b2)) * 2
  gemm_nt<2><<<dim3(16, 64), 256, 0, stream>>>(hbuf, w2, b2, chol, 8192, 1024, 1024, nico);
  // 7) out = x * spectral(chol2)
  spectral_kernel<<<1024, 256, 0, stream>>>(chol, x, out);
}

// Round 3
// 524.661 us; speedup vs baseline: 6.0733x; 3.8460x over previous
//
#include <hip/hip_runtime.h>
#include <cstdint>

// B=4, S=2048, E=1024, H=4, DH=256, DQ=256
typedef _Float16 f16;
typedef unsigned short u16;
typedef __attribute__((ext_vector_type(8))) _Float16 half8;
typedef __attribute__((ext_vector_type(4))) float f32x4;

#define MFMA_F16(a, b, c) __builtin_amdgcn_mfma_f32_16x16x32_f16(a, b, c, 0, 0, 0)

__device__ inline void stage16(const void* g, void* l) {
#if defined(__has_builtin) && __has_builtin(__builtin_amdgcn_global_load_lds)
  __builtin_amdgcn_global_load_lds(
      (const __attribute__((address_space(1))) unsigned*)g,
      (__attribute__((address_space(3))) unsigned*)l, 16, 0, 0);
#else
  *(int4*)l = *(const int4*)g;
#endif
}

// ======================= convert fp32 -> fp16 =======================
__global__ __launch_bounds__(256)
void conv_f16(const float* __restrict__ in, f16* __restrict__ out, int n) {
  int i = (blockIdx.x * 256 + threadIdx.x) * 8;
  if (i >= n) return;
  float4 a = *(const float4*)(in + i);
  float4 b = *(const float4*)(in + i + 4);
  half8 h;
  h[0] = (f16)a.x; h[1] = (f16)a.y; h[2] = (f16)a.z; h[3] = (f16)a.w;
  h[4] = (f16)b.x; h[5] = (f16)b.y; h[6] = (f16)b.z; h[7] = (f16)b.w;
  *(half8*)(out + i) = h;
}

// ======================= fp16 MFMA GEMM: C[M,N] = A[M,K] @ W[N,K]^T + bias =======================
// 128x128 tile, BK=64, 4 waves (each 64x64), double-buffered LDS, global_load_lds staging
// with pre-swizzled source (LDS slot ^= row&7). EPI: 0=bias, 1=bias+gelu, 2=blend.
template<int EPI, int OUTF16>
__global__ __launch_bounds__(256, 2)
void gemm_f16(const f16* __restrict__ A, const f16* __restrict__ W,
              const float* __restrict__ bias, void* __restrict__ Cv,
              int N, int K, const float* __restrict__ aux) {
  __shared__ __align__(16) f16 lds[2][16384];   // [buf][A 128x64 | B 128x64]
  const int tid = threadIdx.x;
  const int lane = tid & 63, w = tid >> 6;
  const int g = lane >> 4, lm = lane & 15;
  const int wr = w >> 1, wc = w & 1;
  const int m0 = blockIdx.y * 128, n0 = blockIdx.x * 128;

  // staging sources: 8x 16B units/thread; unit u: u<1024 -> A row u>>3 slot u&7, else B
  const f16* src[8];
#pragma unroll
  for (int j = 0; j < 8; ++j) {
    int u = j * 256 + tid;
    if (u < 1024) {
      int row = u >> 3, s = u & 7;
      src[j] = A + (size_t)(m0 + row) * K + ((s ^ (row & 7)) << 3);
    } else {
      int v = u - 1024;
      int row = v >> 3, s = v & 7;
      src[j] = W + (size_t)(n0 + row) * K + ((s ^ (row & 7)) << 3);
    }
  }

  f32x4 acc[4][4];
#pragma unroll
  for (int mt = 0; mt < 4; ++mt)
#pragma unroll
    for (int nt = 0; nt < 4; ++nt) acc[mt][nt] = (f32x4){0.f, 0.f, 0.f, 0.f};

  // prologue
#pragma unroll
  for (int j = 0; j < 8; ++j) stage16(src[j], &lds[0][(j * 256 + tid) * 8]);
  __syncthreads();

  const int KT = K >> 6;
#pragma unroll 1
  for (int t = 0; t < KT; ++t) {
    const f16* bufA = lds[t & 1];
    const f16* bufB = bufA + 8192;
    if (t + 1 < KT) {
#pragma unroll
      for (int j = 0; j < 8; ++j) {
        src[j] += 64;
        stage16(src[j], &lds[(t + 1) & 1][(j * 256 + tid) * 8]);
      }
    }
#pragma unroll
    for (int ks = 0; ks < 2; ++ks) {
      half8 a[4], b[4];
#pragma unroll
      for (int mt = 0; mt < 4; ++mt) {
        int row = wr * 64 + mt * 16 + lm;
        a[mt] = *(const half8*)(bufA + row * 64 + (((ks * 4 + g) ^ (row & 7)) << 3));
      }
#pragma unroll
      for (int nt = 0; nt < 4; ++nt) {
        int row = wc * 64 + nt * 16 + lm;
        b[nt] = *(const half8*)(bufB + row * 64 + (((ks * 4 + g) ^ (row & 7)) << 3));
      }
#pragma unroll
      for (int mt = 0; mt < 4; ++mt)
#pragma unroll
        for (int nt = 0; nt < 4; ++nt)
          acc[mt][nt] = MFMA_F16(a[mt], b[nt], acc[mt][nt]);
    }
    __syncthreads();
  }

  // epilogue: D row = g*4+r (+mt*16), col = lm (+nt*16)
  const int crow = m0 + wr * 64 + g * 4;
  const int ccol = n0 + wc * 64 + lm;
#pragma unroll
  for (int nt = 0; nt < 4; ++nt) {
    float bb = bias[ccol + nt * 16];
#pragma unroll
    for (int mt = 0; mt < 4; ++mt) {
#pragma unroll
      for (int r = 0; r < 4; ++r) {
        size_t idx = (size_t)(crow + mt * 16 + r) * N + ccol + nt * 16;
        float v = acc[mt][nt][r] + bb;
        if (EPI == 1) v = 0.5f * v * (1.0f + erff(v * 0.70710678118654752f));
        if (EPI == 2) v = (0.9f * aux[idx] + 0.1f * v) * 2.0f;
        if (OUTF16) ((f16*)Cv)[idx] = (f16)v;
        else        ((float*)Cv)[idx] = v;
      }
    }
  }
}

// ======================= V transpose: qkv fp16 -> Vt[bh][256][2048] fp16 =======================
__global__ __launch_bounds__(256)
void vtrans(const f16* __restrict__ qkv, f16* __restrict__ Vt) {
  __shared__ unsigned vlds[64][65];
  const int tid = threadIdx.x;
  const int bh = blockIdx.x >> 5, st = blockIdx.x & 31;
  const int b = bh >> 2, h = bh & 3;
  const int s0 = st * 64;
  const u16* q16 = (const u16*)qkv;
  u16* v16 = (u16*)Vt;
#pragma unroll 1
  for (int dc = 0; dc < 4; ++dc) {
    __syncthreads();
#pragma unroll 1
    for (int i = 0; i < 16; ++i) {
      int idx = i * 256 + tid;
      int s = idx >> 6, dl = idx & 63;
      vlds[dl][s] = q16[(size_t)(b * 2048 + s0 + s) * 3072 + 2048 + h * 256 + dc * 64 + dl];
    }
    __syncthreads();
#pragma unroll 1
    for (int i = 0; i < 16; ++i) {
      int idx = i * 256 + tid;
      int dl = idx >> 6, s = idx & 63;
      v16[((size_t)bh * 256 + dc * 64 + dl) * 2048 + s0 + s] = (u16)vlds[dl][s];
    }
  }
}

// ======================= fp16 flash attention =======================
// 4 waves x 16 q-rows (BQ=64), TKV=32, double-buffered K/V via global_load_lds,
// XOR-swizzled LDS (K: slot^=(kv&7); V: slot^=((d>>1)&3)). Scale folded into softmax.
__global__ __launch_bounds__(256, 2)
void flash_f16(const f16* __restrict__ qkv, const f16* __restrict__ Vt,
               f16* __restrict__ attn) {
  // LDS (f16 units): K[2][32][256] @0, V[2][256][32] @16384, P[4][16][40] @32768
  __shared__ __align__(16) f16 lds[35328];
  const int tid = threadIdx.x;
  const int lane = tid & 63, w = tid >> 6;
  const int g = lane >> 4, lm = lane & 15;
  const int raw = blockIdx.x;
  const int bh = (raw & 7) * 2 + (raw >> 8);     // 2 bh per XCD
  const int qt = (raw >> 3) & 31;
  const int b = bh >> 2, h = bh & 3;
  const int q0 = qt * 64 + w * 16;
  const float SC = 0.09016844005555896f;          // log2(e)/16

  // Q fragments direct from global (row q0+lm, chunk c*32+g*8)
  half8 qf[8];
  {
    const f16* qp = qkv + (size_t)(b * 2048 + q0 + lm) * 3072 + h * 256 + g * 8;
#pragma unroll
    for (int c = 0; c < 8; ++c) qf[c] = *(const half8*)(qp + c * 32);
  }

  // staging sources (8x 16B units/thread): u<1024 -> K tile, else V tile
  const f16* src[8];
#pragma unroll
  for (int j = 0; j < 8; ++j) {
    int u = j * 256 + tid;
    if (u < 1024) {
      int kv = u >> 5, s = u & 31;
      src[j] = qkv + (size_t)(b * 2048 + kv) * 3072 + 1024 + h * 256 + ((s ^ (kv & 7)) << 3);
    } else {
      int v = u - 1024;
      int d = v >> 2, s = v & 3;
      src[j] = Vt + ((size_t)bh * 256 + d) * 2048 + ((s ^ ((d >> 1) & 3)) << 3);
    }
  }

  f32x4 o[16];
#pragma unroll
  for (int f = 0; f < 16; ++f) o[f] = (f32x4){0.f, 0.f, 0.f, 0.f};
  float m[4] = {-3e38f, -3e38f, -3e38f, -3e38f};
  float l[4] = {0.f, 0.f, 0.f, 0.f};

  // prologue: stage tile 0 into buf0
#pragma unroll
  for (int j = 0; j < 8; ++j) {
    int u = j * 256 + tid;
    f16* dst = (u < 1024) ? &lds[u * 8] : &lds[16384 + (u - 1024) * 8];
    stage16(src[j], dst);
  }
  __syncthreads();

  f16* phf = &lds[32768 + w * 640];

#pragma unroll 1
  for (int t = 0; t < 64; ++t) {
    const int bsel = t & 1;
    if (t < 63) {
      const int nb = bsel ^ 1;
#pragma unroll
      for (int j = 0; j < 8; ++j) {
        src[j] += (j < 4) ? 32 * 3072 : 32;
        int u = j * 256 + tid;
        f16* dst = (u < 1024) ? &lds[nb * 8192 + u * 8]
                              : &lds[16384 + nb * 8192 + (u - 1024) * 8];
        stage16(src[j], dst);
      }
    }
    const f16* kb = &lds[bsel * 8192];
    const f16* vb = &lds[16384 + bsel * 8192];

    // ---- QK^T: S[16q][32kv], A=Q(reg), B=K rows lm / 16+lm ----
    f32x4 s0 = {0.f, 0.f, 0.f, 0.f}, s1 = {0.f, 0.f, 0.f, 0.f};
#pragma unroll
    for (int c = 0; c < 8; ++c) {
      int slot = ((c * 4 + g) ^ (lm & 7)) << 3;
      half8 b0 = *(const half8*)(kb + lm * 256 + slot);
      half8 b1 = *(const half8*)(kb + (16 + lm) * 256 + slot);
      s0 = MFMA_F16(qf[c], b0, s0);
      s1 = MFMA_F16(qf[c], b1, s1);
    }

    // ---- online softmax in log2 domain (scale applied here) ----
    float corr[4], p0[4], p1[4];
#pragma unroll
    for (int r = 0; r < 4; ++r) {
      float a0 = s0[r] * SC, a1 = s1[r] * SC;
      float mx = fmaxf(a0, a1);
      mx = fmaxf(mx, __shfl_xor(mx, 1));
      mx = fmaxf(mx, __shfl_xor(mx, 2));
      mx = fmaxf(mx, __shfl_xor(mx, 4));
      mx = fmaxf(mx, __shfl_xor(mx, 8));
      float mn = fmaxf(m[r], mx);
      corr[r] = exp2f(m[r] - mn);
      m[r] = mn;
      p0[r] = exp2f(a0 - mn);
      p1[r] = exp2f(a1 - mn);
      float rs = p0[r] + p1[r];
      rs += __shfl_xor(rs, 1);
      rs += __shfl_xor(rs, 2);
      rs += __shfl_xor(rs, 4);
      rs += __shfl_xor(rs, 8);
      l[r] = l[r] * corr[r] + rs;
    }

    // ---- P -> fp16, per-wave LDS bounce (C-layout -> A-frag layout) ----
#pragma unroll
    for (int r = 0; r < 4; ++r) {
      int q = g * 4 + r;
      phf[q * 40 + lm]      = (f16)p0[r];
      phf[q * 40 + 16 + lm] = (f16)p1[r];
    }
    // rescale O while P writes land
#pragma unroll
    for (int f = 0; f < 16; ++f)
#pragma unroll
      for (int r = 0; r < 4; ++r) o[f][r] *= corr[r];

    half8 pa = *(const half8*)(phf + lm * 40 + g * 8);

    // ---- PV: O[16q][256d] += P V ----
#pragma unroll
    for (int f = 0; f < 16; ++f) {
      int d = f * 16 + lm;
      half8 bv = *(const half8*)(vb + d * 32 + ((g ^ ((d >> 1) & 3)) << 3));
      o[f] = MFMA_F16(pa, bv, o[f]);
    }

    __syncthreads();   // drains vmcnt (prefetch landed) + lgkm, all waves synced
  }

  // epilogue: attn fp16, row = q0+g*4+r, col = h*256 + f*16+lm
  float inv[4];
#pragma unroll
  for (int r = 0; r < 4; ++r) inv[r] = 1.0f / l[r];
#pragma unroll
  for (int f = 0; f < 16; ++f)
#pragma unroll
    for (int r = 0; r < 4; ++r)
      attn[(size_t)(b * 2048 + q0 + g * 4 + r) * 1024 + h * 256 + f * 16 + lm] =
          (f16)(o[f][r] * inv[r]);
}

// ======================= Spectral attention (unchanged) =======================
__device__ inline float2 cmul(float2 a, float2 b) {
  return make_float2(a.x * b.x - a.y * b.y, a.x * b.y + a.y * b.x);
}

__global__ __launch_bounds__(256)
void spectral_kernel(const float* __restrict__ chol, const float* __restrict__ xin,
                     float* __restrict__ outp) {
  __shared__ float2 data[4][2048];
  __shared__ float2 tw[1024];
  const int tid = threadIdx.x;
  const int b = blockIdx.x >> 8;
  const int qd = blockIdx.x & 255;
  const size_t c0 = (size_t)qd * 4;
  const float* cb = chol + (size_t)b * 2048 * 1024;

  for (int j = tid; j < 1024; j += 256) {
    float ang = -6.2831853071795864769f * (float)j * (1.0f / 2048.0f);
    float sv, cv; sincosf(ang, &sv, &cv);
    tw[j] = make_float2(cv, sv);
  }
  for (int s = tid; s < 2048; s += 256) {
    float4 v = *(const float4*)(cb + (size_t)s * 1024 + c0);
    data[0][s] = make_float2(v.x, 0.f);
    data[1][s] = make_float2(v.y, 0.f);
    data[2][s] = make_float2(v.z, 0.f);
    data[3][s] = make_float2(v.w, 0.f);
  }
  __syncthreads();

  for (int lh = 10; lh >= 0; --lh) {
    const int half = 1 << lh;
#pragma unroll 1
    for (int it = 0; it < 16; ++it) {
      int gg = it * 256 + tid;
      int c = gg >> 10;
      int bf = gg & 1023;
      int j = bf & (half - 1);
      int base = ((bf >> lh) << (lh + 1)) | j;
      float2 a = data[c][base];
      float2 bb = data[c][base + half];
      float2 sum = make_float2(a.x + bb.x, a.y + bb.y);
      float2 dif = make_float2(a.x - bb.x, a.y - bb.y);
      float2 wv = tw[j << (10 - lh)];
      data[c][base] = sum;
      data[c][base + half] = cmul(dif, wv);
    }
    __syncthreads();
  }

#pragma unroll 1
  for (int it = 0; it < 8; ++it) {
    int p = it * 256 + tid;
    unsigned k = __brev((unsigned)p) >> 21;
    float ang = 1.5f * atanf(logf((float)k + 1e-10f));
    float fs, fc; sincosf(ang, &fs, &fc);
    float2 f = make_float2(fc, fs);
    float2 a  = cmul(data[0][p], f);
    float2 xq = cmul(data[1][p], f);
    float2 yq = cmul(data[2][p], f);
    float2 zq = cmul(data[3][p], f);
    float2 a2 = cmul(a, a);
    float2 sx = cmul(xq, xq), sy = cmul(yq, yq), sz = cmul(zq, zq);
    float2 s  = make_float2(sx.x + sy.x + sz.x, sx.y + sy.y + sz.y);
    float2 t3 = make_float2(a2.x - 3.f * s.x, a2.y - 3.f * s.y);
    float2 cf = make_float2(3.f * a2.x - s.x, 3.f * a2.y - s.y);
    data[0][p] = cmul(a, t3);
    data[1][p] = cmul(cf, xq);
    data[2][p] = cmul(cf, yq);
    data[3][p] = cmul(cf, zq);
  }
  __syncthreads();

  for (int lh = 0; lh <= 10; ++lh) {
    const int half = 1 << lh;
#pragma unroll 1
    for (int it = 0; it < 16; ++it) {
      int gg = it * 256 + tid;
      int c = gg >> 10;
      int bf = gg & 1023;
      int j = bf & (half - 1);
      int base = ((bf >> lh) << (lh + 1)) | j;
      float2 a = data[c][base];
      float2 bb = data[c][base + half];
      float2 wv = tw[j << (10 - lh)];
      wv.y = -wv.y;
      float2 bw = cmul(bb, wv);
      data[c][base] = make_float2(a.x + bw.x, a.y + bw.y);
      data[c][base + half] = make_float2(a.x - bw.x, a.y - bw.y);
    }
    __syncthreads();
  }

  const float* xb = xin + (size_t)b * 2048 * 1024;
  float* ob = outp + (size_t)b * 2048 * 1024;
  const float inv = 1.0f / 2048.0f;
  for (int s = tid; s < 2048; s += 256) {
    float4 xv = *(const float4*)(xb + (size_t)s * 1024 + c0);
    float4 o;
    o.x = xv.x * data[0][s].x * inv;
    o.y = xv.y * data[1][s].x * inv;
    o.z = xv.z * data[2][s].x * inv;
    o.w = xv.w * data[3][s].x * inv;
    *(float4*)(ob + (size_t)s * 1024 + c0) = o;
  }
}

// ======================= launch =======================
extern "C" void kernel_launch(void* const* d_in, const int* in_sizes, int n_in,
                              void* d_out, int out_size, void* d_ws, size_t ws_size,
                              hipStream_t stream) {
  const float* x    = (const float*)d_in[0];
  const float* wqkv = (const float*)d_in[1];
  const float* bqkv = (const float*)d_in[2];
  const float* wout = (const float*)d_in[3];
  const float* bout = (const float*)d_in[4];
  const float* w1   = (const float*)d_in[5];
  const float* b1   = (const float*)d_in[6];
  const float* w2   = (const float*)d_in[7];
  const float* b2   = (const float*)d_in[8];
  float* out = (float*)d_out;
  char* wsb = (char*)d_ws;
  const size_t MB = 1048576;

  f16*   xf    = (f16*)(wsb);                //  0..16 MB
  f16*   wqf   = (f16*)(wsb + 16 * MB);      // 16..22
  f16*   wof   = (f16*)(wsb + 22 * MB);      // 22..24
  f16*   w1f   = (f16*)(wsb + 24 * MB);      // 24..26
  f16*   w2f   = (f16*)(wsb + 26 * MB);      // 26..28
  f16*   qkvF  = (f16*)(wsb + 28 * MB);      // 28..76
  f16*   VtF   = (f16*)(wsb + 76 * MB);      // 76..92
  f16*   attnF = (f16*)(wsb + 92 * MB);      // 92..108
  float* nico  = (float*)(wsb + 108 * MB);   // 108..140
  f16*   hF    = (f16*)(wsb + 140 * MB);     // 140..156
  float* chol  = (float*)(wsb + 156 * MB);   // 156..188

  // conversions
  conv_f16<<<4096, 256, 0, stream>>>(x, xf, 8388608);
  conv_f16<<<1536, 256, 0, stream>>>(wqkv, wqf, 3145728);
  conv_f16<<<512, 256, 0, stream>>>(wout, wof, 1048576);
  conv_f16<<<512, 256, 0, stream>>>(w1, w1f, 1048576);
  conv_f16<<<512, 256, 0, stream>>>(w2, w2f, 1048576);

  // 1) qkv = x @ Wqkv^T + b   (fp16 out)
  gemm_f16<0, 1><<<dim3(24, 64), 256, 0, stream>>>(xf, wqf, bqkv, qkvF, 3072, 1024, nullptr);
  // 2) V transpose
  vtrans<<<512, 256, 0, stream>>>(qkvF, VtF);
  // 3) flash attention (fp16)
  flash_f16<<<512, 256, 0, stream>>>(qkvF, VtF, attnF);
  // 4) nicotinic = attn @ Wout^T + b  (fp32 out)
  gemm_f16<0, 0><<<dim3(8, 64), 256, 0, stream>>>(attnF, wof, bout, nico, 1024, 1024, nullptr);
  // 5) h = gelu(x @ W1^T + b1)  (fp16 out)
  gemm_f16<1, 1><<<dim3(8, 64), 256, 0, stream>>>(xf, w1f, b1, hF, 1024, 1024, nullptr);
  // 6) chol2 = (0.9*nico + 0.1*(h @ W2^T + b2)) * 2  (fp32 out)
  gemm_f16<2, 0><<<dim3(8, 64), 256, 0, stream>>>(hF, w2f, b2, chol, 1024, 1024, nico);
  // 7) out = x * spectral(chol2)
  spectral_kernel<<<1024, 256, 0, stream>>>(chol, x, out);
}